// Round 2
// baseline (423.655 us; speedup 1.0000x reference)
//
#include <hip/hip_runtime.h>

static constexpr int B_ = 512, N_ = 32, D_ = 256, K_ = 8;
static constexpr int E1 = 40, E2 = 6;          // ee MLP dims 256->40->6->1
static constexpr int N1 = 81, N2 = 25, N3 = 8; // en MLP dims 256->81->25->8
static constexpr int XP = 257;                 // xs LDS row pad (257 % 32 == 1 -> conflict-free)
static constexpr float LN2f = 0.69314718055994530942f;

// shifted softplus: log(0.5*exp(x)+0.5) = softplus(x) - ln2, numerically stable
__device__ __forceinline__ float sspf(float x) {
    float ax = fabsf(x);
    float e  = __expf(-ax);
    return fmaxf(x, 0.f) + __logf(1.f + e) - LN2f;
}

// ---------------- kernel B: electron-nucleus part --------------------------
// writes bf_nuc [B,N,3] fp32 and cutoff [B,N] fp32 to workspace
__global__ __launch_bounds__(256) void k_en(
    const float* __restrict__ rs, const float* __restrict__ xs,
    const float* __restrict__ coords,
    const float* __restrict__ nw1, const float* __restrict__ nb1,
    const float* __restrict__ nw2, const float* __restrict__ nb2,
    const float* __restrict__ nw3, const float* __restrict__ nb3,
    float* __restrict__ bfn_ws, float* __restrict__ cut_ws)
{
    __shared__ alignas(16) float xs_s[N_ * XP];
    __shared__ float h1_s[N_ * 84];
    __shared__ float h2_s[N_ * 26];
    __shared__ float rs_s[N_ * 3];
    __shared__ float nw2_s[N1 * N2];
    __shared__ float nw3_s[N2 * N3];
    __shared__ float nb1_s[N1];
    __shared__ float nb2_s[N2];
    __shared__ float nb3_s[N3];
    __shared__ float co_s[K_ * 3];

    const int b = blockIdx.x, t = threadIdx.x;

    // stage xs[b] (32x256 fp32) into LDS with row pad XP
    {
        const float4* src = (const float4*)(xs + (size_t)b * N_ * D_);
        #pragma unroll
        for (int u = 0; u < 8; ++u) {
            int q = t + 256 * u;            // 2048 float4 total
            float4 v = src[q];
            int row = q >> 6, col = (q & 63) * 4;
            float* dst = &xs_s[row * XP + col];
            dst[0] = v.x; dst[1] = v.y; dst[2] = v.z; dst[3] = v.w;
        }
    }
    if (t < N_ * 3) rs_s[t] = rs[b * N_ * 3 + t];
    for (int i = t; i < N1 * N2; i += 256) nw2_s[i] = nw2[i];
    if (t < N2 * N3) nw3_s[t] = nw3[t];
    if (t < N1) nb1_s[t] = nb1[t];
    if (t < N2) nb2_s[t] = nb2[t];
    if (t < N3) nb3_s[t] = nb3[t];
    if (t < K_ * 3) co_s[t] = coords[t];
    __syncthreads();

    const int r = t >> 3, s = t & 7;

    // ---- layer 1: 256 -> 81, thread (r,s) computes n0..n0+10 (11 wide, store 10 unless s==7)
    {
        const int n0 = s * 10;
        float acc[11];
        #pragma unroll
        for (int u = 0; u < 11; ++u) acc[u] = 0.f;
        const int rb = r * XP;
        for (int k = 0; k < D_; ++k) {
            float xv = xs_s[rb + k];
            const float* wrow = nw1 + k * N1 + n0;
            #pragma unroll
            for (int u = 0; u < 11; ++u) acc[u] = fmaf(xv, wrow[u], acc[u]);
        }
        #pragma unroll
        for (int u = 0; u < 11; ++u) {
            int n = n0 + u;
            if (u < 10 || s == 7) h1_s[r * 84 + n] = sspf(acc[u] + nb1_s[n]);
        }
    }
    __syncthreads();

    // ---- layer 2: 81 -> 25, thread (r,s) computes n0=3s..+3 (4 wide, store 3 unless s==7)
    {
        const int n0 = 3 * s;
        float acc[4] = {0.f, 0.f, 0.f, 0.f};
        const int rb = r * 84;
        for (int kk = 0; kk < N1; ++kk) {
            float hv = h1_s[rb + kk];
            const float* wrow = nw2_s + kk * N2 + n0;
            #pragma unroll
            for (int u = 0; u < 4; ++u) acc[u] = fmaf(hv, wrow[u], acc[u]);
        }
        #pragma unroll
        for (int u = 0; u < 4; ++u) {
            int n = n0 + u;
            if (u < 3 || s == 7) h2_s[r * 26 + n] = sspf(acc[u] + nb2_s[n]);
        }
    }
    __syncthreads();

    // ---- layer 3 + bf_nuc + cutoff; lane s owns nucleus s
    {
        float w = nb3_s[s];
        const int rb = r * 26;
        #pragma unroll
        for (int kk = 0; kk < N2; ++kk)
            w = fmaf(h2_s[rb + kk], nw3_s[kk * N3 + s], w);

        float dx = rs_s[r * 3 + 0] - co_s[s * 3 + 0];
        float dy = rs_s[r * 3 + 1] - co_s[s * 3 + 1];
        float dz = rs_s[r * 3 + 2] - co_s[s * 3 + 2];
        float cx = w * dx, cy = w * dy, cz = w * dz;
        #pragma unroll
        for (int m = 1; m < 8; m <<= 1) {
            cx += __shfl_xor(cx, m);
            cy += __shfl_xor(cy, m);
            cz += __shfl_xor(cz, m);
        }
        float rr  = sqrtf(dx * dx + dy * dy + dz * dz);
        float xsc = 2.f * rr;                 // r / L with L = 0.5
        float cf  = (xsc < 0.5f) ? xsc * xsc * (6.f - 8.f * xsc + 3.f * xsc * xsc) : 1.f;
        #pragma unroll
        for (int m = 1; m < 8; m <<= 1) cf *= __shfl_xor(cf, m);

        if (s == 0) {
            int gi = b * N_ + r;
            bfn_ws[gi * 3 + 0] = cx;
            bfn_ws[gi * 3 + 1] = cy;
            bfn_ws[gi * 3 + 2] = cz;
            cut_ws[gi] = cf;
        }
    }
}

// ---------------- kernel A: electron-electron part + combine ---------------
__global__ __launch_bounds__(256, 2) void k_ee(
    const float* __restrict__ rs, const float* __restrict__ xs,
    const float* __restrict__ ew1, const float* __restrict__ eb1,
    const float* __restrict__ ew2, const float* __restrict__ eb2,
    const float* __restrict__ ew3, const float* __restrict__ eb3,
    const float* __restrict__ bfn_ws, const float* __restrict__ cut_ws,
    float* __restrict__ out)
{
    __shared__ alignas(16) float xs_s[N_ * XP];
    __shared__ alignas(16) float ew1_s[D_ * E1];   // [256][40] fp32, 40 KB
    __shared__ float eb1_s[E1];
    __shared__ alignas(16) float ew2_s[E1 * 8];    // [40][8] padded
    __shared__ float eb2_s[8];
    __shared__ float ew3_s[E2];
    __shared__ float eb3_sv[1];
    __shared__ float rs_s[N_ * 3];
    __shared__ float bfe_s[N_ * 3];

    const int b = blockIdx.x, t = threadIdx.x;

    // stage xs[b]
    {
        const float4* src = (const float4*)(xs + (size_t)b * N_ * D_);
        #pragma unroll
        for (int u = 0; u < 8; ++u) {
            int q = t + 256 * u;
            float4 v = src[q];
            int row = q >> 6, col = (q & 63) * 4;
            float* dst = &xs_s[row * XP + col];
            dst[0] = v.x; dst[1] = v.y; dst[2] = v.z; dst[3] = v.w;
        }
    }
    // stage ew1 fp32 (exactly 40*256 = 2560 float4)
    {
        const float4* src = (const float4*)ew1;
        float4* dst = (float4*)ew1_s;
        #pragma unroll
        for (int u = 0; u < 10; ++u) {
            int idx = t + 256 * u;
            dst[idx] = src[idx];
        }
    }
    if (t < E1) eb1_s[t] = eb1[t];
    if (t < E1 * E2) { int kk = t / 6, n = t - kk * 6; ew2_s[kk * 8 + n] = ew2[t]; }
    if (t < E1) { ew2_s[t * 8 + 6] = 0.f; ew2_s[t * 8 + 7] = 0.f; }  // zero pads
    if (t < E2) ew3_s[t] = ew3[t];
    if (t == 0) eb3_sv[0] = eb3[0];
    if (t < 8) eb2_s[t] = (t < E2) ? eb2[t] : 0.f;
    if (t < N_ * 3) rs_s[t] = rs[b * N_ * 3 + t];
    __syncthreads();

    const int j = t & 31, g = t >> 5;
    const int jb = j * XP;
    const float rjx = rs_s[j * 3 + 0], rjy = rs_s[j * 3 + 1], rjz = rs_s[j * 3 + 2];
    float w3v[E2];
    #pragma unroll
    for (int u = 0; u < E2; ++u) w3v[u] = ew3_s[u];
    const float eb3v = eb3_sv[0];

    auto tail = [&](float (&acc)[E1], int i) {
        // bias + ssp (in place)
        #pragma unroll
        for (int u = 0; u < E1; ++u) acc[u] = sspf(acc[u] + eb1_s[u]);
        // layer 2: 40 -> 6
        float h2a[6] = {0.f, 0.f, 0.f, 0.f, 0.f, 0.f};
        #pragma unroll
        for (int kk = 0; kk < E1; ++kk) {
            const float4* w2r = (const float4*)&ew2_s[kk * 8];
            float4 a = w2r[0], bb = w2r[1];
            float hv = acc[kk];
            h2a[0] = fmaf(hv, a.x, h2a[0]);
            h2a[1] = fmaf(hv, a.y, h2a[1]);
            h2a[2] = fmaf(hv, a.z, h2a[2]);
            h2a[3] = fmaf(hv, a.w, h2a[3]);
            h2a[4] = fmaf(hv, bb.x, h2a[4]);
            h2a[5] = fmaf(hv, bb.y, h2a[5]);
        }
        // layer 3: 6 -> 1 (with ssp on h2)
        float w = eb3v;
        #pragma unroll
        for (int m = 0; m < E2; ++m) w = fmaf(sspf(h2a[m] + eb2_s[m]), w3v[m], w);
        // contribution w * (rs[i] - rs[j]); i==j self-cancels (diff = 0)
        float cx = w * (rs_s[i * 3 + 0] - rjx);
        float cy = w * (rs_s[i * 3 + 1] - rjy);
        float cz = w * (rs_s[i * 3 + 2] - rjz);
        #pragma unroll
        for (int m = 1; m < 32; m <<= 1) {
            cx += __shfl_xor(cx, m);
            cy += __shfl_xor(cy, m);
            cz += __shfl_xor(cz, m);
        }
        if (j == 0) {
            bfe_s[i * 3 + 0] = cx;
            bfe_s[i * 3 + 1] = cy;
            bfe_s[i * 3 + 2] = cz;
        }
    };

    #pragma unroll 1
    for (int pass = 0; pass < 2; ++pass) {
        const int i0 = g + 16 * pass, i1 = i0 + 8;
        const int i0b = i0 * XP, i1b = i1 * XP;
        float acc0[E1], acc1[E1];
        #pragma unroll
        for (int u = 0; u < E1; ++u) { acc0[u] = 0.f; acc1[u] = 0.f; }

        for (int k = 0; k < D_; ++k) {
            float jv = xs_s[jb + k];
            float p0 = jv * xs_s[i0b + k];
            float p1 = jv * xs_s[i1b + k];
            const float4* row4 = (const float4*)&ew1_s[k * E1];
            #pragma unroll
            for (int q = 0; q < 10; ++q) {
                float4 wv = row4[q];
                acc0[4 * q + 0] = fmaf(p0, wv.x, acc0[4 * q + 0]);
                acc0[4 * q + 1] = fmaf(p0, wv.y, acc0[4 * q + 1]);
                acc0[4 * q + 2] = fmaf(p0, wv.z, acc0[4 * q + 2]);
                acc0[4 * q + 3] = fmaf(p0, wv.w, acc0[4 * q + 3]);
                acc1[4 * q + 0] = fmaf(p1, wv.x, acc1[4 * q + 0]);
                acc1[4 * q + 1] = fmaf(p1, wv.y, acc1[4 * q + 1]);
                acc1[4 * q + 2] = fmaf(p1, wv.z, acc1[4 * q + 2]);
                acc1[4 * q + 3] = fmaf(p1, wv.w, acc1[4 * q + 3]);
            }
        }
        tail(acc0, i0);
        tail(acc1, i1);
    }
    __syncthreads();

    // combine and write output (fp32)
    if (t < N_ * 3) {
        int r = t / 3, c = t - 3 * r;
        int gi = b * N_ + r;
        float val = rs_s[t] + 1e-4f * cut_ws[gi] * (bfe_s[t] + bfn_ws[gi * 3 + c]);
        out[(size_t)b * (N_ * 3) + t] = val;
    }
}

extern "C" void kernel_launch(void* const* d_in, const int* in_sizes, int n_in,
                              void* d_out, int out_size, void* d_ws, size_t ws_size,
                              hipStream_t stream)
{
    const float* rs     = (const float*)d_in[0];
    const float* xs     = (const float*)d_in[1];
    const float* coords = (const float*)d_in[2];
    const float* ew1    = (const float*)d_in[3];
    const float* eb1    = (const float*)d_in[4];
    const float* ew2    = (const float*)d_in[5];
    const float* eb2    = (const float*)d_in[6];
    const float* ew3    = (const float*)d_in[7];
    const float* eb3    = (const float*)d_in[8];
    const float* nw1    = (const float*)d_in[9];
    const float* nb1    = (const float*)d_in[10];
    const float* nw2    = (const float*)d_in[11];
    const float* nb2    = (const float*)d_in[12];
    const float* nw3    = (const float*)d_in[13];
    const float* nb3    = (const float*)d_in[14];

    float* ws  = (float*)d_ws;
    float* bfn = ws;                  // 49152 floats
    float* cut = ws + 49152;          // 16384 floats

    k_en<<<B_, 256, 0, stream>>>(rs, xs, coords, nw1, nb1, nw2, nb2, nw3, nb3, bfn, cut);
    k_ee<<<B_, 256, 0, stream>>>(rs, xs, ew1, eb1, ew2, eb2, ew3, eb3, bfn, cut,
                                 (float*)d_out);
}